// Round 7
// baseline (148.844 us; speedup 1.0000x reference)
//
#include <hip/hip_runtime.h>

typedef unsigned short u16;
typedef unsigned int   u32;
typedef __attribute__((ext_vector_type(8))) short bf16x8;
typedef __attribute__((ext_vector_type(4))) float f32x4;

#define LROW 4096
#define NB   8192
#define PCOL 720
#define NPAD 768
#define HH   2048
#define INV_SQRT2F 0.70710678118654752440f

// ws layout: xbf | G | std
#define WS_XBF_BYTES ((size_t)67108864)           // 8192*4096*2
#define WS_G_BYTES   ((size_t)6291456)            // 768*4096*2
#define WS_MIN       (WS_XBF_BYTES + WS_G_BYTES + (size_t)NB * 4)

__device__ __forceinline__ u16 f2bf(float f) {
    union { float f; u32 u; } v; v.f = f;
    u32 r = v.u + 0x7FFFu + ((v.u >> 16) & 1u);
    return (u16)(r >> 16);
}

#define SWZ(i) ((i) ^ (((i) >> 5) & 31))

// ---------------------------------------------------------------------------
// Kernel P: per-row moving-average (via prefix sum), std (ddof=1), x -> bf16
// ---------------------------------------------------------------------------
__global__ __launch_bounds__(256) void prep_rows(const float* __restrict__ x,
                                                 u16* __restrict__ xbf,
                                                 float* __restrict__ stdv) {
    __shared__ float S[LROW];
    __shared__ float wred[4];
    __shared__ float ends[2];
    __shared__ float rred[8];
    const int tid = threadIdx.x;
    const int lane = tid & 63, wv = tid >> 6;
    const size_t b = blockIdx.x;

    const float4* xr4 = (const float4*)(x + b * LROW);
    float4 q0 = xr4[tid * 4 + 0], q1 = xr4[tid * 4 + 1];
    float4 q2 = xr4[tid * 4 + 2], q3 = xr4[tid * 4 + 3];
    float r[16];
    r[0]=q0.x; r[1]=q0.y; r[2]=q0.z; r[3]=q0.w;
    r[4]=q1.x; r[5]=q1.y; r[6]=q1.z; r[7]=q1.w;
    r[8]=q2.x; r[9]=q2.y; r[10]=q2.z; r[11]=q2.w;
    r[12]=q3.x; r[13]=q3.y; r[14]=q3.z; r[15]=q3.w;

    float ps[16];
    float a = 0.f;
    #pragma unroll
    for (int k = 0; k < 16; ++k) { a += r[k]; ps[k] = a; }
    const float segsum = a;

    float v = segsum;
    #pragma unroll
    for (int off = 1; off < 64; off <<= 1) {
        float o = __shfl_up(v, off);
        if (lane >= off) v += o;
    }
    if (lane == 63) wred[wv] = v;
    if (tid == 0)   ends[0] = r[0];
    if (tid == 255) ends[1] = r[15];
    __syncthreads();

    float wbase = 0.f;
    #pragma unroll
    for (int w = 0; w < 4; ++w) if (w < wv) wbase += wred[w];
    const float ebase = wbase + v - segsum;

    #pragma unroll
    for (int k = 0; k < 16; ++k) {
        const int i = (tid << 4) + k;
        S[SWZ(i)] = ebase + ps[k];
    }
    __syncthreads();

    const float x0 = ends[0], xl = ends[1];
    float s1 = 0.f, s2 = 0.f;
    u16 ob[16];
    #pragma unroll
    for (int k = 0; k < 16; ++k) {
        const int i = (tid << 4) + k;
        int h = i + 12; h = h > LROW - 1 ? LROW - 1 : h;
        float wsum = S[SWZ(h)];
        if (i >= 13) wsum -= S[SWZ(i - 13)];
        if (i < 12) wsum += (float)(12 - i) * x0;
        if (i > LROW - 13) wsum += (float)(i - (LROW - 13)) * xl;
        const float xi = r[k];
        const float rr = xi - wsum * 0.04f;
        s1 += rr; s2 += rr * rr;
        ob[k] = f2bf(xi);
    }

    uint4 o0, o1;
    o0.x = (u32)ob[0]  | ((u32)ob[1]  << 16);
    o0.y = (u32)ob[2]  | ((u32)ob[3]  << 16);
    o0.z = (u32)ob[4]  | ((u32)ob[5]  << 16);
    o0.w = (u32)ob[6]  | ((u32)ob[7]  << 16);
    o1.x = (u32)ob[8]  | ((u32)ob[9]  << 16);
    o1.y = (u32)ob[10] | ((u32)ob[11] << 16);
    o1.z = (u32)ob[12] | ((u32)ob[13] << 16);
    o1.w = (u32)ob[14] | ((u32)ob[15] << 16);
    uint4* op = (uint4*)(xbf + b * LROW + ((size_t)tid << 4));
    op[0] = o0; op[1] = o1;

    #pragma unroll
    for (int off = 32; off; off >>= 1) {
        s1 += __shfl_down(s1, off);
        s2 += __shfl_down(s2, off);
    }
    if (lane == 0) { rred[wv * 2] = s1; rred[wv * 2 + 1] = s2; }
    __syncthreads();
    if (tid == 0) {
        const float S1 = rred[0] + rred[2] + rred[4] + rred[6];
        const float S2 = rred[1] + rred[3] + rred[5] + rred[7];
        const float mean = S1 / (float)LROW;
        float var = (S2 - (float)LROW * mean * mean) / (float)(LROW - 1);
        var = var < 0.f ? 0.f : var;
        stdv[b] = sqrtf(var) + 1e-5f;
    }
}

// ---------------------------------------------------------------------------
// Kernel W: fold weights into G[p][l] (bf16), rows 720..767 zero-padded.
// ---------------------------------------------------------------------------
__global__ __launch_bounds__(256) void prep_weights(const float* __restrict__ Wt,
                                                    const float* __restrict__ Wlo,
                                                    const float* __restrict__ Whi,
                                                    u16* __restrict__ Gm) {
    __shared__ float S[LROW];
    __shared__ float wred[4];
    __shared__ float sred[4];
    const int tid = threadIdx.x;
    const int lane = tid & 63, wv = tid >> 6;
    const int p = blockIdx.x;
    u16* grow = Gm + (size_t)p * LROW;
    if (p >= PCOL) {
        uint4 z; z.x = z.y = z.z = z.w = 0u;
        uint4* g4 = (uint4*)grow;
        for (int i = tid; i < LROW / 8; i += 256) g4[i] = z;
        return;
    }
    const float4* wt4 = (const float4*)(Wt + (size_t)p * LROW);
    float4 q0 = wt4[tid * 4 + 0], q1 = wt4[tid * 4 + 1];
    float4 q2 = wt4[tid * 4 + 2], q3 = wt4[tid * 4 + 3];
    const float4* lo4 = (const float4*)(Wlo + (size_t)p * HH);
    const float4* hi4 = (const float4*)(Whi + (size_t)p * HH);
    float4 a0 = lo4[tid * 2 + 0], a1 = lo4[tid * 2 + 1];
    float4 b0 = hi4[tid * 2 + 0], b1 = hi4[tid * 2 + 1];

    float w[16];
    w[0]=q0.x; w[1]=q0.y; w[2]=q0.z; w[3]=q0.w;
    w[4]=q1.x; w[5]=q1.y; w[6]=q1.z; w[7]=q1.w;
    w[8]=q2.x; w[9]=q2.y; w[10]=q2.z; w[11]=q2.w;
    w[12]=q3.x; w[13]=q3.y; w[14]=q3.z; w[15]=q3.w;
    float lv[8] = {a0.x,a0.y,a0.z,a0.w,a1.x,a1.y,a1.z,a1.w};
    float hv[8] = {b0.x,b0.y,b0.z,b0.w,b1.x,b1.y,b1.z,b1.w};

    float u[16], z_[16];
    float slo = 0.f;
    #pragma unroll
    for (int j = 0; j < 8; ++j) {
        u[2*j]   = (lv[j] + hv[j]) * INV_SQRT2F;
        u[2*j+1] = (lv[j] - hv[j]) * INV_SQRT2F;
        slo += lv[j];
    }
    #pragma unroll
    for (int k = 0; k < 16; ++k) z_[k] = w[k] - u[k];

    float ps[16];
    float a = 0.f;
    #pragma unroll
    for (int k = 0; k < 16; ++k) { a += z_[k]; ps[k] = a; }
    const float segsum = a;

    float v = segsum;
    #pragma unroll
    for (int off = 1; off < 64; off <<= 1) {
        float o = __shfl_up(v, off);
        if (lane >= off) v += o;
    }
    if (lane == 63) wred[wv] = v;
    #pragma unroll
    for (int off = 32; off; off >>= 1) slo += __shfl_down(slo, off);
    if (lane == 0) sred[wv] = slo;
    __syncthreads();

    float wbase = 0.f;
    #pragma unroll
    for (int ww = 0; ww < 4; ++ww) if (ww < wv) wbase += wred[ww];
    const float ebase = wbase + v - segsum;
    const float SLO = sred[0] + sred[1] + sred[2] + sred[3];

    #pragma unroll
    for (int k = 0; k < 16; ++k) {
        const int i = (tid << 4) + k;
        S[SWZ(i)] = ebase + ps[k];
    }
    __syncthreads();

    const float coef = -1.4142135623730951f * SLO / (float)LROW;
    u16 ob[16];
    #pragma unroll
    for (int k = 0; k < 16; ++k) {
        const int l = (tid << 4) + k;
        float zT;
        if (l == 0) {
            float acc = 0.f;
            for (int m = 0; m <= 12; ++m) acc += S[SWZ(m)];
            zT = acc * 0.04f;
        } else if (l == LROW - 1) {
            float acc = 0.f;
            for (int m = 0; m <= 12; ++m) acc += S[SWZ(LROW - 2 - m)];
            zT = (13.f * S[SWZ(LROW - 1)] - acc) * 0.04f;
        } else {
            int h = l + 12; h = h > LROW - 1 ? LROW - 1 : h;
            float t_ = S[SWZ(h)];
            if (l >= 13) t_ -= S[SWZ(l - 13)];
            zT = t_ * 0.04f;
        }
        float c;
        const int dmin = l < (LROW - 1 - l) ? l : (LROW - 1 - l);
        if (dmin >= 12)      c = 0.f;
        else if (dmin == 0)  c = -66.f / 25.f;
        else                 c = (float)(12 - dmin) * 0.04f;
        ob[k] = f2bf(zT + u[k] + coef * c);
    }

    uint4 o0, o1;
    o0.x = (u32)ob[0]  | ((u32)ob[1]  << 16);
    o0.y = (u32)ob[2]  | ((u32)ob[3]  << 16);
    o0.z = (u32)ob[4]  | ((u32)ob[5]  << 16);
    o0.w = (u32)ob[6]  | ((u32)ob[7]  << 16);
    o1.x = (u32)ob[8]  | ((u32)ob[9]  << 16);
    o1.y = (u32)ob[10] | ((u32)ob[11] << 16);
    o1.z = (u32)ob[12] | ((u32)ob[13] << 16);
    o1.w = (u32)ob[14] | ((u32)ob[15] << 16);
    uint4* op = (uint4*)(grow + ((size_t)tid << 4));
    op[0] = o0; op[1] = o1;
}

// ---------------------------------------------------------------------------
// Kernel G: fused GEMM, BM=128 BN=96 BK=64, 512 thr = 8 waves (2m x 2n x 2kp),
// 64 iters, one barrier/iter. A: LDS 3-deep (every wave stages 2 gld16,
// proven XOR swizzle, lead-2). B: global->register direct via asm
// global_load_dwordx4 (2 named sets, lead-1, L2-resident panel). Both waits
// are counted vmcnt(5); never drain in main loop. k-parity reduce via LDS +
// fused bias/std epilogue. 52KB LDS -> 2 blocks/CU = 4 waves/SIMD.
// ---------------------------------------------------------------------------
typedef __attribute__((address_space(1))) void gvoid;
typedef __attribute__((address_space(3))) void lvoid;
#define GLD16(g, l_) __builtin_amdgcn_global_load_lds((gvoid*)(g), (lvoid*)(l_), 16, 0, 0)
#define MF(a, b, c) __builtin_amdgcn_mfma_f32_16x16x32_bf16(a, b, c, 0, 0, 0)
#define GL16(dst, p) asm volatile("global_load_dwordx4 %0, %1, off" : "=&v"(dst) : "v"(p) : "memory")

#define ABUF 16384            // 128 rows x 128B

#define STAGE_A(T, DB) do { \
    char* d_ = Sm + (DB) * ABUF + wid * 2048; \
    const size_t go_ = (size_t)(T) * 128; \
    GLD16(sA0 + go_, d_); \
    GLD16(sA1 + go_, d_ + 1024); \
} while (0)

#define ITER(T, AR, SAB, C0, C1, C2, N0, N1, N2, V1, V2, SA, SB) do { \
    asm volatile("s_waitcnt vmcnt(" #V1 ")" ::: "memory"); \
    __builtin_amdgcn_s_barrier(); \
    __builtin_amdgcn_sched_barrier(0); \
    if (SA) STAGE_A((T) + 2, SAB); \
    if (SB) { \
        const size_t go_ = (size_t)((T) + 1) * 128; \
        GL16(N0, pb0 + go_); \
        GL16(N1, pb1 + go_); \
        GL16(N2, pb2 + go_); \
    } \
    asm volatile("s_waitcnt vmcnt(" #V2 ")" ::: "memory"); \
    __builtin_amdgcn_sched_barrier(0); \
    const char* ab_ = Sm + (AR) * ABUF + aro; \
    bf16x8 a0_ = *(const bf16x8*)(ab_); \
    bf16x8 a1_ = *(const bf16x8*)(ab_ + 2048); \
    bf16x8 a2_ = *(const bf16x8*)(ab_ + 4096); \
    bf16x8 a3_ = *(const bf16x8*)(ab_ + 6144); \
    asm volatile("s_waitcnt lgkmcnt(0)" ::: "memory"); \
    __builtin_amdgcn_sched_barrier(0); \
    __builtin_amdgcn_s_setprio(1); \
    acc[0][0]=MF(a0_,C0,acc[0][0]); acc[0][1]=MF(a0_,C1,acc[0][1]); acc[0][2]=MF(a0_,C2,acc[0][2]); \
    acc[1][0]=MF(a1_,C0,acc[1][0]); acc[1][1]=MF(a1_,C1,acc[1][1]); acc[1][2]=MF(a1_,C2,acc[1][2]); \
    acc[2][0]=MF(a2_,C0,acc[2][0]); acc[2][1]=MF(a2_,C1,acc[2][1]); acc[2][2]=MF(a2_,C2,acc[2][2]); \
    acc[3][0]=MF(a3_,C0,acc[3][0]); acc[3][1]=MF(a3_,C1,acc[3][1]); acc[3][2]=MF(a3_,C2,acc[3][2]); \
    __builtin_amdgcn_s_setprio(0); \
} while (0)

__global__ __launch_bounds__(512, 4) void gemm_fused(const u16* __restrict__ Abf,
                                                     const u16* __restrict__ Gbf,
                                                     const float* __restrict__ bt,
                                                     const float* __restrict__ bl,
                                                     const float* __restrict__ bh,
                                                     const float* __restrict__ stdv,
                                                     float* __restrict__ out) {
    __shared__ __align__(16) char Sm[53248];   // A 3x16KB; epilogue reduce reuses
    const int tid = threadIdx.x;
    const int l = tid & 63, wid = tid >> 6;          // wid 0..7
    const int kp = wid & 1, wm = (wid >> 1) & 1, wn = wid >> 2;

    // XCD-chunked swizzle: 512 = 8 XCDs x 64; n fastest within chunk
    const int orig = blockIdx.x;
    const int chunk = orig & 7, pos = orig >> 3;
    const int bx = pos & 7;
    const int by = (chunk << 3) + (pos >> 3);
    const int m0 = by * 128;
    const int n0 = bx * 96;

    // ---- A staging: each wave stages rows [wid*16, +16) via 2 gld16 ----
    // pre-swizzled source slot = (l&7)^(l>>3)  ==> LDS(row,s) = A(row, s^(row&7))
    const int sgb = (((l & 7) ^ (l >> 3)) << 4);
    const char* sA0 = (const char*)Abf + ((size_t)(m0 + wid * 16 + (l >> 3)) << 13) + sgb;
    const char* sA1 = (const char*)Abf + ((size_t)(m0 + wid * 16 + 8 + (l >> 3)) << 13) + sgb;

    // ---- A frag read offsets: k-slice [kp*32,+32): slots (kp*4 .. +4) ^ swz ----
    const int slot = ((kp << 2) + (l >> 4)) ^ (l & 7);
    const int aro = (wm * 64 + (l & 15)) * 128 + (slot << 4);

    // ---- B: direct global->reg, per-lane 16B; row wn*48+nf*16+(l&15),
    //      k byte = t*128 + kp*64 + (l>>4)*16 ----
    const char* pb0 = (const char*)Gbf + ((size_t)(n0 + wn * 48 +  0 + (l & 15)) << 13) + kp * 64 + ((l >> 4) << 4);
    const char* pb1 = (const char*)Gbf + ((size_t)(n0 + wn * 48 + 16 + (l & 15)) << 13) + kp * 64 + ((l >> 4) << 4);
    const char* pb2 = (const char*)Gbf + ((size_t)(n0 + wn * 48 + 32 + (l & 15)) << 13) + kp * 64 + ((l >> 4) << 4);

    f32x4 acc[4][3] = {};
    bf16x8 B00, B01, B02, B10, B11, B12;

    // ---- prologue: A(0),A(1) staged; B(0) issued. outstanding = 7 ----
    STAGE_A(0, 0);
    STAGE_A(1, 1);
    GL16(B00, pb0); GL16(B01, pb1); GL16(B02, pb2);

    for (int t = 0; t < 60; t += 6) {
        ITER(t + 0, 0, 2, B00, B01, B02, B10, B11, B12, 5, 5, 1, 1);
        ITER(t + 1, 1, 0, B10, B11, B12, B00, B01, B02, 5, 5, 1, 1);
        ITER(t + 2, 2, 1, B00, B01, B02, B10, B11, B12, 5, 5, 1, 1);
        ITER(t + 3, 0, 2, B10, B11, B12, B00, B01, B02, 5, 5, 1, 1);
        ITER(t + 4, 1, 0, B00, B01, B02, B10, B11, B12, 5, 5, 1, 1);
        ITER(t + 5, 2, 1, B10, B11, B12, B00, B01, B02, 5, 5, 1, 1);
    }
    ITER(60, 0, 2, B00, B01, B02, B10, B11, B12, 5, 5, 1, 1);
    ITER(61, 1, 0, B10, B11, B12, B00, B01, B02, 5, 5, 1, 1);
    ITER(62, 2, 0, B00, B01, B02, B10, B11, B12, 5, 3, 0, 1);
    ITER(63, 0, 0, B10, B11, B12, B00, B01, B02, 3, 0, 0, 0);

    // ---- cross-parity reduce (kp1 -> LDS, kp0 adds) + fused bias epilogue ----
    __syncthreads();
    float* red = (float*)Sm;
    const int pb_ = (wm * 2 + wn) * 3264;   // floats; col stride 68 floats (272B)
    const int rr_ = (l >> 4) << 2;
    const int cc_ = l & 15;
    if (kp == 1) {
        #pragma unroll
        for (int m = 0; m < 4; ++m)
            #pragma unroll
            for (int n = 0; n < 3; ++n)
                *(f32x4*)(red + pb_ + (n * 16 + cc_) * 68 + m * 16 + rr_) = acc[m][n];
    }
    __syncthreads();
    if (kp == 0) {
        const int crow = m0 + wm * 64 + rr_;
        const int ccol = n0 + wn * 48 + cc_;
        float btv[3], bsv[3];
        #pragma unroll
        for (int n = 0; n < 3; ++n) {
            const int col = ccol + n * 16;
            if (col < PCOL) { btv[n] = bt[col]; bsv[n] = bl[col] + bh[col]; }
            else            { btv[n] = 0.f; bsv[n] = 0.f; }
        }
        #pragma unroll
        for (int m = 0; m < 4; ++m) {
            const int row = crow + m * 16;
            const float4 sv = *(const float4*)(stdv + row);
            #pragma unroll
            for (int n = 0; n < 3; ++n) {
                const int col = ccol + n * 16;
                if (col < PCOL) {
                    const f32x4 pv = *(const f32x4*)(red + pb_ + (n * 16 + cc_) * 68 + m * 16 + rr_);
                    float* orow = out + (size_t)row * PCOL + col;
                    #pragma unroll
                    for (int j = 0; j < 4; ++j) {
                        const float s = (j == 0) ? sv.x : (j == 1) ? sv.y : (j == 2) ? sv.z : sv.w;
                        orow[(size_t)j * PCOL] = acc[m][n][j] + pv[j] + btv[n] + s * bsv[n];
                    }
                }
            }
        }
    }
}

// ---------------------------------------------------------------------------
extern "C" void kernel_launch(void* const* d_in, const int* in_sizes, int n_in,
                              void* d_out, int out_size, void* d_ws, size_t ws_size,
                              hipStream_t stream) {
    (void)in_sizes; (void)n_in; (void)out_size;
    if (ws_size < WS_MIN) return;

    const float* x  = (const float*)d_in[0];
    const float* Wt = (const float*)d_in[1];
    const float* bt = (const float*)d_in[2];
    const float* Wl = (const float*)d_in[3];
    const float* bl = (const float*)d_in[4];
    const float* Wh = (const float*)d_in[5];
    const float* bh = (const float*)d_in[6];
    float* out = (float*)d_out;

    char* ws = (char*)d_ws;
    u16*   xbf = (u16*)ws;
    u16*   Gm  = (u16*)(ws + WS_XBF_BYTES);
    float* sd  = (float*)(ws + WS_XBF_BYTES + WS_G_BYTES);

    prep_rows<<<NB, 256, 0, stream>>>(x, xbf, sd);
    prep_weights<<<NPAD, 256, 0, stream>>>(Wt, Wl, Wh, Gm);
    gemm_fused<<<512, 512, 0, stream>>>(xbf, Gm, bt, bl, bh, sd, out);
}

// Round 8
// 97.285 us; speedup vs baseline: 1.5300x; 1.5300x over previous
//
#include <hip/hip_runtime.h>

typedef unsigned short u16;
typedef unsigned int   u32;
typedef __attribute__((ext_vector_type(8))) short bf16x8;
typedef __attribute__((ext_vector_type(4))) float f32x4;

#define LROW 4096
#define NB   8192
#define PCOL 720
#define NPAD 768
#define HH   2048
#define INV_SQRT2F 0.70710678118654752440f

// ws layout: xbf | G | std
#define WS_XBF_BYTES ((size_t)67108864)           // 8192*4096*2
#define WS_G_BYTES   ((size_t)6291456)            // 768*4096*2
#define WS_MIN       (WS_XBF_BYTES + WS_G_BYTES + (size_t)NB * 4)

__device__ __forceinline__ u16 f2bf(float f) {
    union { float f; u32 u; } v; v.f = f;
    u32 r = v.u + 0x7FFFu + ((v.u >> 16) & 1u);
    return (u16)(r >> 16);
}

#define SWZ(i) ((i) ^ (((i) >> 5) & 31))

// ---------------------------------------------------------------------------
// Kernel P: per-row moving-average (via prefix sum), std (ddof=1), x -> bf16
// ---------------------------------------------------------------------------
__global__ __launch_bounds__(256) void prep_rows(const float* __restrict__ x,
                                                 u16* __restrict__ xbf,
                                                 float* __restrict__ stdv) {
    __shared__ float S[LROW];
    __shared__ float wred[4];
    __shared__ float ends[2];
    __shared__ float rred[8];
    const int tid = threadIdx.x;
    const int lane = tid & 63, wv = tid >> 6;
    const size_t b = blockIdx.x;

    const float4* xr4 = (const float4*)(x + b * LROW);
    float4 q0 = xr4[tid * 4 + 0], q1 = xr4[tid * 4 + 1];
    float4 q2 = xr4[tid * 4 + 2], q3 = xr4[tid * 4 + 3];
    float r[16];
    r[0]=q0.x; r[1]=q0.y; r[2]=q0.z; r[3]=q0.w;
    r[4]=q1.x; r[5]=q1.y; r[6]=q1.z; r[7]=q1.w;
    r[8]=q2.x; r[9]=q2.y; r[10]=q2.z; r[11]=q2.w;
    r[12]=q3.x; r[13]=q3.y; r[14]=q3.z; r[15]=q3.w;

    float ps[16];
    float a = 0.f;
    #pragma unroll
    for (int k = 0; k < 16; ++k) { a += r[k]; ps[k] = a; }
    const float segsum = a;

    float v = segsum;
    #pragma unroll
    for (int off = 1; off < 64; off <<= 1) {
        float o = __shfl_up(v, off);
        if (lane >= off) v += o;
    }
    if (lane == 63) wred[wv] = v;
    if (tid == 0)   ends[0] = r[0];
    if (tid == 255) ends[1] = r[15];
    __syncthreads();

    float wbase = 0.f;
    #pragma unroll
    for (int w = 0; w < 4; ++w) if (w < wv) wbase += wred[w];
    const float ebase = wbase + v - segsum;

    #pragma unroll
    for (int k = 0; k < 16; ++k) {
        const int i = (tid << 4) + k;
        S[SWZ(i)] = ebase + ps[k];
    }
    __syncthreads();

    const float x0 = ends[0], xl = ends[1];
    float s1 = 0.f, s2 = 0.f;
    u16 ob[16];
    #pragma unroll
    for (int k = 0; k < 16; ++k) {
        const int i = (tid << 4) + k;
        int h = i + 12; h = h > LROW - 1 ? LROW - 1 : h;
        float wsum = S[SWZ(h)];
        if (i >= 13) wsum -= S[SWZ(i - 13)];
        if (i < 12) wsum += (float)(12 - i) * x0;
        if (i > LROW - 13) wsum += (float)(i - (LROW - 13)) * xl;
        const float xi = r[k];
        const float rr = xi - wsum * 0.04f;
        s1 += rr; s2 += rr * rr;
        ob[k] = f2bf(xi);
    }

    uint4 o0, o1;
    o0.x = (u32)ob[0]  | ((u32)ob[1]  << 16);
    o0.y = (u32)ob[2]  | ((u32)ob[3]  << 16);
    o0.z = (u32)ob[4]  | ((u32)ob[5]  << 16);
    o0.w = (u32)ob[6]  | ((u32)ob[7]  << 16);
    o1.x = (u32)ob[8]  | ((u32)ob[9]  << 16);
    o1.y = (u32)ob[10] | ((u32)ob[11] << 16);
    o1.z = (u32)ob[12] | ((u32)ob[13] << 16);
    o1.w = (u32)ob[14] | ((u32)ob[15] << 16);
    uint4* op = (uint4*)(xbf + b * LROW + ((size_t)tid << 4));
    op[0] = o0; op[1] = o1;

    #pragma unroll
    for (int off = 32; off; off >>= 1) {
        s1 += __shfl_down(s1, off);
        s2 += __shfl_down(s2, off);
    }
    if (lane == 0) { rred[wv * 2] = s1; rred[wv * 2 + 1] = s2; }
    __syncthreads();
    if (tid == 0) {
        const float S1 = rred[0] + rred[2] + rred[4] + rred[6];
        const float S2 = rred[1] + rred[3] + rred[5] + rred[7];
        const float mean = S1 / (float)LROW;
        float var = (S2 - (float)LROW * mean * mean) / (float)(LROW - 1);
        var = var < 0.f ? 0.f : var;
        stdv[b] = sqrtf(var) + 1e-5f;
    }
}

// ---------------------------------------------------------------------------
// Kernel W: fold weights into G[p][l] (bf16), rows 720..767 zero-padded.
// ---------------------------------------------------------------------------
__global__ __launch_bounds__(256) void prep_weights(const float* __restrict__ Wt,
                                                    const float* __restrict__ Wlo,
                                                    const float* __restrict__ Whi,
                                                    u16* __restrict__ Gm) {
    __shared__ float S[LROW];
    __shared__ float wred[4];
    __shared__ float sred[4];
    const int tid = threadIdx.x;
    const int lane = tid & 63, wv = tid >> 6;
    const int p = blockIdx.x;
    u16* grow = Gm + (size_t)p * LROW;
    if (p >= PCOL) {
        uint4 z; z.x = z.y = z.z = z.w = 0u;
        uint4* g4 = (uint4*)grow;
        for (int i = tid; i < LROW / 8; i += 256) g4[i] = z;
        return;
    }
    const float4* wt4 = (const float4*)(Wt + (size_t)p * LROW);
    float4 q0 = wt4[tid * 4 + 0], q1 = wt4[tid * 4 + 1];
    float4 q2 = wt4[tid * 4 + 2], q3 = wt4[tid * 4 + 3];
    const float4* lo4 = (const float4*)(Wlo + (size_t)p * HH);
    const float4* hi4 = (const float4*)(Whi + (size_t)p * HH);
    float4 a0 = lo4[tid * 2 + 0], a1 = lo4[tid * 2 + 1];
    float4 b0 = hi4[tid * 2 + 0], b1 = hi4[tid * 2 + 1];

    float w[16];
    w[0]=q0.x; w[1]=q0.y; w[2]=q0.z; w[3]=q0.w;
    w[4]=q1.x; w[5]=q1.y; w[6]=q1.z; w[7]=q1.w;
    w[8]=q2.x; w[9]=q2.y; w[10]=q2.z; w[11]=q2.w;
    w[12]=q3.x; w[13]=q3.y; w[14]=q3.z; w[15]=q3.w;
    float lv[8] = {a0.x,a0.y,a0.z,a0.w,a1.x,a1.y,a1.z,a1.w};
    float hv[8] = {b0.x,b0.y,b0.z,b0.w,b1.x,b1.y,b1.z,b1.w};

    float u[16], z_[16];
    float slo = 0.f;
    #pragma unroll
    for (int j = 0; j < 8; ++j) {
        u[2*j]   = (lv[j] + hv[j]) * INV_SQRT2F;
        u[2*j+1] = (lv[j] - hv[j]) * INV_SQRT2F;
        slo += lv[j];
    }
    #pragma unroll
    for (int k = 0; k < 16; ++k) z_[k] = w[k] - u[k];

    float ps[16];
    float a = 0.f;
    #pragma unroll
    for (int k = 0; k < 16; ++k) { a += z_[k]; ps[k] = a; }
    const float segsum = a;

    float v = segsum;
    #pragma unroll
    for (int off = 1; off < 64; off <<= 1) {
        float o = __shfl_up(v, off);
        if (lane >= off) v += o;
    }
    if (lane == 63) wred[wv] = v;
    #pragma unroll
    for (int off = 32; off; off >>= 1) slo += __shfl_down(slo, off);
    if (lane == 0) sred[wv] = slo;
    __syncthreads();

    float wbase = 0.f;
    #pragma unroll
    for (int ww = 0; ww < 4; ++ww) if (ww < wv) wbase += wred[ww];
    const float ebase = wbase + v - segsum;
    const float SLO = sred[0] + sred[1] + sred[2] + sred[3];

    #pragma unroll
    for (int k = 0; k < 16; ++k) {
        const int i = (tid << 4) + k;
        S[SWZ(i)] = ebase + ps[k];
    }
    __syncthreads();

    const float coef = -1.4142135623730951f * SLO / (float)LROW;
    u16 ob[16];
    #pragma unroll
    for (int k = 0; k < 16; ++k) {
        const int l = (tid << 4) + k;
        float zT;
        if (l == 0) {
            float acc = 0.f;
            for (int m = 0; m <= 12; ++m) acc += S[SWZ(m)];
            zT = acc * 0.04f;
        } else if (l == LROW - 1) {
            float acc = 0.f;
            for (int m = 0; m <= 12; ++m) acc += S[SWZ(LROW - 2 - m)];
            zT = (13.f * S[SWZ(LROW - 1)] - acc) * 0.04f;
        } else {
            int h = l + 12; h = h > LROW - 1 ? LROW - 1 : h;
            float t_ = S[SWZ(h)];
            if (l >= 13) t_ -= S[SWZ(l - 13)];
            zT = t_ * 0.04f;
        }
        float c;
        const int dmin = l < (LROW - 1 - l) ? l : (LROW - 1 - l);
        if (dmin >= 12)      c = 0.f;
        else if (dmin == 0)  c = -66.f / 25.f;
        else                 c = (float)(12 - dmin) * 0.04f;
        ob[k] = f2bf(zT + u[k] + coef * c);
    }

    uint4 o0, o1;
    o0.x = (u32)ob[0]  | ((u32)ob[1]  << 16);
    o0.y = (u32)ob[2]  | ((u32)ob[3]  << 16);
    o0.z = (u32)ob[4]  | ((u32)ob[5]  << 16);
    o0.w = (u32)ob[6]  | ((u32)ob[7]  << 16);
    o1.x = (u32)ob[8]  | ((u32)ob[9]  << 16);
    o1.y = (u32)ob[10] | ((u32)ob[11] << 16);
    o1.z = (u32)ob[12] | ((u32)ob[13] << 16);
    o1.w = (u32)ob[14] | ((u32)ob[15] << 16);
    uint4* op = (uint4*)(grow + ((size_t)tid << 4));
    op[0] = o0; op[1] = o1;
}

// ---------------------------------------------------------------------------
// Kernel G: fused GEMM, BM=128 BN=96 BK=64, 256 thr = 4 waves (2m x 2kp),
// wave tile 64x96 (4m x 6n frags of 16x16x32). A LDS 3-deep (16KB bufs),
// B LDS 2-deep (12KB bufs); EVERY wave stages 4 A-gld16 + 3 B-gld16 per iter
// (uniform counted vmcnt(4): issue B(t+1) before A(t+2)). R6-verbatim XOR
// slot swizzle (pre-swizzled global source). One barrier/iter. kp-pair
// reduce via LDS + fused bias/std epilogue. 72KB LDS -> 2 blocks/CU.
// ---------------------------------------------------------------------------
typedef __attribute__((address_space(1))) void gvoid;
typedef __attribute__((address_space(3))) void lvoid;
#define GLD16(g, l_) __builtin_amdgcn_global_load_lds((gvoid*)(g), (lvoid*)(l_), 16, 0, 0)
#define MF(a, b, c) __builtin_amdgcn_mfma_f32_16x16x32_bf16(a, b, c, 0, 0, 0)

#define ABUFB 16384           // 128 rows x 128B
#define BBASE 49152           // A: 3 x 16KB
#define BBUFB 12288           // 96 rows x 128B

#define STAGE_B(T, DB) do { \
    char* d_ = Sm + BBASE + (DB) * BBUFB + wid * 3072; \
    const size_t go_ = (size_t)(T) * 128; \
    GLD16(sB0 + go_, d_); \
    GLD16(sB0 + go_ + 65536, d_ + 1024); \
    GLD16(sB0 + go_ + 131072, d_ + 2048); \
} while (0)

#define STAGE_A(T, DB) do { \
    char* d_ = Sm + (DB) * ABUFB + wid * 4096; \
    const size_t go_ = (size_t)(T) * 128; \
    GLD16(sA0 + go_, d_); \
    GLD16(sA0 + go_ + 65536, d_ + 1024); \
    GLD16(sA0 + go_ + 131072, d_ + 2048); \
    GLD16(sA0 + go_ + 196608, d_ + 3072); \
} while (0)

#define ITER(T, AB, BB, SBB, SAB, VM, SB, SA) do { \
    asm volatile("s_waitcnt vmcnt(" #VM ")" ::: "memory"); \
    __builtin_amdgcn_s_barrier(); \
    __builtin_amdgcn_sched_barrier(0); \
    if (SB) STAGE_B((T) + 1, SBB); \
    if (SA) STAGE_A((T) + 2, SAB); \
    __builtin_amdgcn_sched_barrier(0); \
    const char* a_ = Sm + (AB) * ABUFB + aro; \
    const char* b_ = Sm + BBASE + (BB) * BBUFB + bro; \
    bf16x8 A0 = *(const bf16x8*)(a_); \
    bf16x8 A1 = *(const bf16x8*)(a_ + 2048); \
    bf16x8 A2 = *(const bf16x8*)(a_ + 4096); \
    bf16x8 A3 = *(const bf16x8*)(a_ + 6144); \
    bf16x8 B0 = *(const bf16x8*)(b_); \
    bf16x8 B1 = *(const bf16x8*)(b_ + 2048); \
    bf16x8 B2 = *(const bf16x8*)(b_ + 4096); \
    bf16x8 B3 = *(const bf16x8*)(b_ + 6144); \
    bf16x8 B4 = *(const bf16x8*)(b_ + 8192); \
    bf16x8 B5 = *(const bf16x8*)(b_ + 10240); \
    asm volatile("s_waitcnt lgkmcnt(0)" ::: "memory"); \
    __builtin_amdgcn_sched_barrier(0); \
    __builtin_amdgcn_s_setprio(1); \
    acc[0][0]=MF(A0,B0,acc[0][0]); acc[0][1]=MF(A0,B1,acc[0][1]); acc[0][2]=MF(A0,B2,acc[0][2]); \
    acc[0][3]=MF(A0,B3,acc[0][3]); acc[0][4]=MF(A0,B4,acc[0][4]); acc[0][5]=MF(A0,B5,acc[0][5]); \
    acc[1][0]=MF(A1,B0,acc[1][0]); acc[1][1]=MF(A1,B1,acc[1][1]); acc[1][2]=MF(A1,B2,acc[1][2]); \
    acc[1][3]=MF(A1,B3,acc[1][3]); acc[1][4]=MF(A1,B4,acc[1][4]); acc[1][5]=MF(A1,B5,acc[1][5]); \
    acc[2][0]=MF(A2,B0,acc[2][0]); acc[2][1]=MF(A2,B1,acc[2][1]); acc[2][2]=MF(A2,B2,acc[2][2]); \
    acc[2][3]=MF(A2,B3,acc[2][3]); acc[2][4]=MF(A2,B4,acc[2][4]); acc[2][5]=MF(A2,B5,acc[2][5]); \
    acc[3][0]=MF(A3,B0,acc[3][0]); acc[3][1]=MF(A3,B1,acc[3][1]); acc[3][2]=MF(A3,B2,acc[3][2]); \
    acc[3][3]=MF(A3,B3,acc[3][3]); acc[3][4]=MF(A3,B4,acc[3][4]); acc[3][5]=MF(A3,B5,acc[3][5]); \
    __builtin_amdgcn_s_setprio(0); \
} while (0)

__global__ __launch_bounds__(256, 2) void gemm_fused(const u16* __restrict__ Abf,
                                                     const u16* __restrict__ Gbf,
                                                     const float* __restrict__ bt,
                                                     const float* __restrict__ bl,
                                                     const float* __restrict__ bh,
                                                     const float* __restrict__ stdv,
                                                     float* __restrict__ out) {
    __shared__ __align__(16) char Sm[73728];   // A 3x16KB | B 2x12KB
    const int tid = threadIdx.x;
    const int l = tid & 63, wid = tid >> 6;    // wid 0..3
    const int wm = wid & 1, kp = wid >> 1;

    // XCD-chunked swizzle: 512 = 8 XCDs x 64; n fastest within chunk
    const int orig = blockIdx.x;
    const int chunk = orig & 7, pos = orig >> 3;
    const int bx = pos & 7;
    const int by = (chunk << 3) + (pos >> 3);
    const int m0 = by * 128;
    const int n0 = bx * 96;

    // ---- staging: each gld16 covers 8 rows x 128B; pre-swizzled source
    //      slot = (l&7)^(l>>3)  ==>  LDS(row, s) = M(row, s ^ (row&7))
    const int sgb = (((l & 7) ^ (l >> 3)) << 4);
    // wave wid stages A rows [wid*32, +32) (4 instrs), B rows [wid*24, +24) (3)
    const char* sA0 = (const char*)Abf + ((size_t)(m0 + wid * 32 + (l >> 3)) << 13) + sgb;
    const char* sB0 = (const char*)Gbf + ((size_t)(n0 + wid * 24 + (l >> 3)) << 13) + sgb;

    // ---- fragment read offsets (16x16x32): row base + swizzled k-slot ----
    // A: row = wm*64 + fm*16 + (l&15); k-slot = kp*4 + (l>>4), phys ^ (l&7)
    const int slot16 = ((((kp << 2) + (l >> 4)) ^ (l & 7)) << 4);
    const int aro = (wm * 64 + (l & 15)) * 128 + slot16;   // fm adds 2048
    const int bro = (l & 15) * 128 + slot16;               // fn adds 2048

    f32x4 acc[4][6] = {};

    // ---- prologue: A(0)->buf0, A(1)->buf1, B(0)->buf0 (11 loads/wave) ----
    STAGE_A(0, 0);
    STAGE_A(1, 1);
    STAGE_B(0, 0);

    //          T  AB BB SBB SAB VM SB SA
    ITER(        0, 0, 0, 1,  2, 0, 1, 1);
    for (int t = 1; t <= 55; t += 6) {
        ITER(t    , 1, 1, 0, 0, 4, 1, 1);
        ITER(t + 1, 2, 0, 1, 1, 4, 1, 1);
        ITER(t + 2, 0, 1, 0, 2, 4, 1, 1);
        ITER(t + 3, 1, 0, 1, 0, 4, 1, 1);
        ITER(t + 4, 2, 1, 0, 1, 4, 1, 1);
        ITER(t + 5, 0, 0, 1, 2, 4, 1, 1);
    }
    ITER(61, 1, 1, 0, 0, 4, 1, 1);
    ITER(62, 2, 0, 1, 0, 4, 1, 0);
    ITER(63, 0, 1, 0, 0, 0, 0, 0);

    // ---- kp-pair reduce (kp1 -> LDS, kp0 adds) + fused bias epilogue ----
    __syncthreads();
    float* red = (float*)Sm;
    const int rr = (l >> 4) << 2;
    const int cc = l & 15;
    const int rbase = wm * 6528;              // 96 cols x 68 floats
    if (kp == 1) {
        #pragma unroll
        for (int m = 0; m < 4; ++m)
            #pragma unroll
            for (int n = 0; n < 6; ++n)
                *(f32x4*)(red + rbase + (n * 16 + cc) * 68 + m * 16 + rr) = acc[m][n];
    }
    __syncthreads();
    if (kp == 0) {
        const int crow = m0 + wm * 64 + rr;
        const int ccol = n0 + cc;
        float btv[6], bsv[6];
        #pragma unroll
        for (int n = 0; n < 6; ++n) {
            const int col = ccol + n * 16;
            if (col < PCOL) { btv[n] = bt[col]; bsv[n] = bl[col] + bh[col]; }
            else            { btv[n] = 0.f; bsv[n] = 0.f; }
        }
        #pragma unroll
        for (int m = 0; m < 4; ++m) {
            const int row = crow + m * 16;
            const float4 sv = *(const float4*)(stdv + row);
            #pragma unroll
            for (int n = 0; n < 6; ++n) {
                const int col = ccol + n * 16;
                if (col < PCOL) {
                    const f32x4 pv = *(const f32x4*)(red + rbase + (n * 16 + cc) * 68 + m * 16 + rr);
                    float* orow = out + (size_t)row * PCOL + col;
                    #pragma unroll
                    for (int j = 0; j < 4; ++j) {
                        const float s = (j == 0) ? sv.x : (j == 1) ? sv.y : (j == 2) ? sv.z : sv.w;
                        orow[(size_t)j * PCOL] = acc[m][n][j] + pv[j] + btv[n] + s * bsv[n];
                    }
                }
            }
        }
    }
}

// ---------------------------------------------------------------------------
extern "C" void kernel_launch(void* const* d_in, const int* in_sizes, int n_in,
                              void* d_out, int out_size, void* d_ws, size_t ws_size,
                              hipStream_t stream) {
    (void)in_sizes; (void)n_in; (void)out_size;
    if (ws_size < WS_MIN) return;

    const float* x  = (const float*)d_in[0];
    const float* Wt = (const float*)d_in[1];
    const float* bt = (const float*)d_in[2];
    const float* Wl = (const float*)d_in[3];
    const float* bl = (const float*)d_in[4];
    const float* Wh = (const float*)d_in[5];
    const float* bh = (const float*)d_in[6];
    float* out = (float*)d_out;

    char* ws = (char*)d_ws;
    u16*   xbf = (u16*)ws;
    u16*   Gm  = (u16*)(ws + WS_XBF_BYTES);
    float* sd  = (float*)(ws + WS_XBF_BYTES + WS_G_BYTES);

    prep_rows<<<NB, 256, 0, stream>>>(x, xbf, sd);
    prep_weights<<<NPAD, 256, 0, stream>>>(Wt, Wl, Wh, Gm);
    gemm_fused<<<512, 256, 0, stream>>>(xbf, Gm, bt, bl, bh, sd, out);
}

// Round 9
// 95.390 us; speedup vs baseline: 1.5604x; 1.0199x over previous
//
#include <hip/hip_runtime.h>

typedef unsigned short u16;
typedef unsigned int   u32;
typedef __attribute__((ext_vector_type(8))) short bf16x8;
typedef __attribute__((ext_vector_type(4))) float f32x4;

#define LROW 4096
#define NB   8192
#define PCOL 720
#define NPAD 768
#define HH   2048
#define INV_SQRT2F 0.70710678118654752440f

// ws layout: xbf | G | std
#define WS_XBF_BYTES ((size_t)67108864)           // 8192*4096*2
#define WS_G_BYTES   ((size_t)6291456)            // 768*4096*2
#define WS_MIN       (WS_XBF_BYTES + WS_G_BYTES + (size_t)NB * 4)

__device__ __forceinline__ u16 f2bf(float f) {
    union { float f; u32 u; } v; v.f = f;
    u32 r = v.u + 0x7FFFu + ((v.u >> 16) & 1u);
    return (u16)(r >> 16);
}

#define SWZ(i) ((i) ^ (((i) >> 5) & 31))

// ---------------------------------------------------------------------------
// Kernel P: per-row moving-average (via prefix sum), std (ddof=1), x -> bf16
// ---------------------------------------------------------------------------
__global__ __launch_bounds__(256) void prep_rows(const float* __restrict__ x,
                                                 u16* __restrict__ xbf,
                                                 float* __restrict__ stdv) {
    __shared__ float S[LROW];
    __shared__ float wred[4];
    __shared__ float ends[2];
    __shared__ float rred[8];
    const int tid = threadIdx.x;
    const int lane = tid & 63, wv = tid >> 6;
    const size_t b = blockIdx.x;

    const float4* xr4 = (const float4*)(x + b * LROW);
    float4 q0 = xr4[tid * 4 + 0], q1 = xr4[tid * 4 + 1];
    float4 q2 = xr4[tid * 4 + 2], q3 = xr4[tid * 4 + 3];
    float r[16];
    r[0]=q0.x; r[1]=q0.y; r[2]=q0.z; r[3]=q0.w;
    r[4]=q1.x; r[5]=q1.y; r[6]=q1.z; r[7]=q1.w;
    r[8]=q2.x; r[9]=q2.y; r[10]=q2.z; r[11]=q2.w;
    r[12]=q3.x; r[13]=q3.y; r[14]=q3.z; r[15]=q3.w;

    float ps[16];
    float a = 0.f;
    #pragma unroll
    for (int k = 0; k < 16; ++k) { a += r[k]; ps[k] = a; }
    const float segsum = a;

    float v = segsum;
    #pragma unroll
    for (int off = 1; off < 64; off <<= 1) {
        float o = __shfl_up(v, off);
        if (lane >= off) v += o;
    }
    if (lane == 63) wred[wv] = v;
    if (tid == 0)   ends[0] = r[0];
    if (tid == 255) ends[1] = r[15];
    __syncthreads();

    float wbase = 0.f;
    #pragma unroll
    for (int w = 0; w < 4; ++w) if (w < wv) wbase += wred[w];
    const float ebase = wbase + v - segsum;

    #pragma unroll
    for (int k = 0; k < 16; ++k) {
        const int i = (tid << 4) + k;
        S[SWZ(i)] = ebase + ps[k];
    }
    __syncthreads();

    const float x0 = ends[0], xl = ends[1];
    float s1 = 0.f, s2 = 0.f;
    u16 ob[16];
    #pragma unroll
    for (int k = 0; k < 16; ++k) {
        const int i = (tid << 4) + k;
        int h = i + 12; h = h > LROW - 1 ? LROW - 1 : h;
        float wsum = S[SWZ(h)];
        if (i >= 13) wsum -= S[SWZ(i - 13)];
        if (i < 12) wsum += (float)(12 - i) * x0;
        if (i > LROW - 13) wsum += (float)(i - (LROW - 13)) * xl;
        const float xi = r[k];
        const float rr = xi - wsum * 0.04f;
        s1 += rr; s2 += rr * rr;
        ob[k] = f2bf(xi);
    }

    uint4 o0, o1;
    o0.x = (u32)ob[0]  | ((u32)ob[1]  << 16);
    o0.y = (u32)ob[2]  | ((u32)ob[3]  << 16);
    o0.z = (u32)ob[4]  | ((u32)ob[5]  << 16);
    o0.w = (u32)ob[6]  | ((u32)ob[7]  << 16);
    o1.x = (u32)ob[8]  | ((u32)ob[9]  << 16);
    o1.y = (u32)ob[10] | ((u32)ob[11] << 16);
    o1.z = (u32)ob[12] | ((u32)ob[13] << 16);
    o1.w = (u32)ob[14] | ((u32)ob[15] << 16);
    uint4* op = (uint4*)(xbf + b * LROW + ((size_t)tid << 4));
    op[0] = o0; op[1] = o1;

    #pragma unroll
    for (int off = 32; off; off >>= 1) {
        s1 += __shfl_down(s1, off);
        s2 += __shfl_down(s2, off);
    }
    if (lane == 0) { rred[wv * 2] = s1; rred[wv * 2 + 1] = s2; }
    __syncthreads();
    if (tid == 0) {
        const float S1 = rred[0] + rred[2] + rred[4] + rred[6];
        const float S2 = rred[1] + rred[3] + rred[5] + rred[7];
        const float mean = S1 / (float)LROW;
        float var = (S2 - (float)LROW * mean * mean) / (float)(LROW - 1);
        var = var < 0.f ? 0.f : var;
        stdv[b] = sqrtf(var) + 1e-5f;
    }
}

// ---------------------------------------------------------------------------
// Kernel W: fold weights into G[p][l] (bf16), rows 720..767 zero-padded.
// ---------------------------------------------------------------------------
__global__ __launch_bounds__(256) void prep_weights(const float* __restrict__ Wt,
                                                    const float* __restrict__ Wlo,
                                                    const float* __restrict__ Whi,
                                                    u16* __restrict__ Gm) {
    __shared__ float S[LROW];
    __shared__ float wred[4];
    __shared__ float sred[4];
    const int tid = threadIdx.x;
    const int lane = tid & 63, wv = tid >> 6;
    const int p = blockIdx.x;
    u16* grow = Gm + (size_t)p * LROW;
    if (p >= PCOL) {
        uint4 z; z.x = z.y = z.z = z.w = 0u;
        uint4* g4 = (uint4*)grow;
        for (int i = tid; i < LROW / 8; i += 256) g4[i] = z;
        return;
    }
    const float4* wt4 = (const float4*)(Wt + (size_t)p * LROW);
    float4 q0 = wt4[tid * 4 + 0], q1 = wt4[tid * 4 + 1];
    float4 q2 = wt4[tid * 4 + 2], q3 = wt4[tid * 4 + 3];
    const float4* lo4 = (const float4*)(Wlo + (size_t)p * HH);
    const float4* hi4 = (const float4*)(Whi + (size_t)p * HH);
    float4 a0 = lo4[tid * 2 + 0], a1 = lo4[tid * 2 + 1];
    float4 b0 = hi4[tid * 2 + 0], b1 = hi4[tid * 2 + 1];

    float w[16];
    w[0]=q0.x; w[1]=q0.y; w[2]=q0.z; w[3]=q0.w;
    w[4]=q1.x; w[5]=q1.y; w[6]=q1.z; w[7]=q1.w;
    w[8]=q2.x; w[9]=q2.y; w[10]=q2.z; w[11]=q2.w;
    w[12]=q3.x; w[13]=q3.y; w[14]=q3.z; w[15]=q3.w;
    float lv[8] = {a0.x,a0.y,a0.z,a0.w,a1.x,a1.y,a1.z,a1.w};
    float hv[8] = {b0.x,b0.y,b0.z,b0.w,b1.x,b1.y,b1.z,b1.w};

    float u[16], z_[16];
    float slo = 0.f;
    #pragma unroll
    for (int j = 0; j < 8; ++j) {
        u[2*j]   = (lv[j] + hv[j]) * INV_SQRT2F;
        u[2*j+1] = (lv[j] - hv[j]) * INV_SQRT2F;
        slo += lv[j];
    }
    #pragma unroll
    for (int k = 0; k < 16; ++k) z_[k] = w[k] - u[k];

    float ps[16];
    float a = 0.f;
    #pragma unroll
    for (int k = 0; k < 16; ++k) { a += z_[k]; ps[k] = a; }
    const float segsum = a;

    float v = segsum;
    #pragma unroll
    for (int off = 1; off < 64; off <<= 1) {
        float o = __shfl_up(v, off);
        if (lane >= off) v += o;
    }
    if (lane == 63) wred[wv] = v;
    #pragma unroll
    for (int off = 32; off; off >>= 1) slo += __shfl_down(slo, off);
    if (lane == 0) sred[wv] = slo;
    __syncthreads();

    float wbase = 0.f;
    #pragma unroll
    for (int ww = 0; ww < 4; ++ww) if (ww < wv) wbase += wred[ww];
    const float ebase = wbase + v - segsum;
    const float SLO = sred[0] + sred[1] + sred[2] + sred[3];

    #pragma unroll
    for (int k = 0; k < 16; ++k) {
        const int i = (tid << 4) + k;
        S[SWZ(i)] = ebase + ps[k];
    }
    __syncthreads();

    const float coef = -1.4142135623730951f * SLO / (float)LROW;
    u16 ob[16];
    #pragma unroll
    for (int k = 0; k < 16; ++k) {
        const int l = (tid << 4) + k;
        float zT;
        if (l == 0) {
            float acc = 0.f;
            for (int m = 0; m <= 12; ++m) acc += S[SWZ(m)];
            zT = acc * 0.04f;
        } else if (l == LROW - 1) {
            float acc = 0.f;
            for (int m = 0; m <= 12; ++m) acc += S[SWZ(LROW - 2 - m)];
            zT = (13.f * S[SWZ(LROW - 1)] - acc) * 0.04f;
        } else {
            int h = l + 12; h = h > LROW - 1 ? LROW - 1 : h;
            float t_ = S[SWZ(h)];
            if (l >= 13) t_ -= S[SWZ(l - 13)];
            zT = t_ * 0.04f;
        }
        float c;
        const int dmin = l < (LROW - 1 - l) ? l : (LROW - 1 - l);
        if (dmin >= 12)      c = 0.f;
        else if (dmin == 0)  c = -66.f / 25.f;
        else                 c = (float)(12 - dmin) * 0.04f;
        ob[k] = f2bf(zT + u[k] + coef * c);
    }

    uint4 o0, o1;
    o0.x = (u32)ob[0]  | ((u32)ob[1]  << 16);
    o0.y = (u32)ob[2]  | ((u32)ob[3]  << 16);
    o0.z = (u32)ob[4]  | ((u32)ob[5]  << 16);
    o0.w = (u32)ob[6]  | ((u32)ob[7]  << 16);
    o1.x = (u32)ob[8]  | ((u32)ob[9]  << 16);
    o1.y = (u32)ob[10] | ((u32)ob[11] << 16);
    o1.z = (u32)ob[12] | ((u32)ob[13] << 16);
    o1.w = (u32)ob[14] | ((u32)ob[15] << 16);
    uint4* op = (uint4*)(grow + ((size_t)tid << 4));
    op[0] = o0; op[1] = o1;
}

// ---------------------------------------------------------------------------
// Kernel G: fused GEMM, BM=128 BN=96 BK=64, 256 thr = 4 waves (2m x 2kp),
// wave tile 64x96. R8-verbatim staging/swizzle/frag-offset math.
// NEW (R9): register-double-buffered fragments, read ONE ITER AHEAD:
//   iter t: lgkm(0)+vmcnt(0) [retire frags(t) reads + stage(t+1), issued
//   last iter]; barrier; STAGE(t+2)->buf[t&1]; ds_read frags(t+1) -> NXT;
//   24 MFMA on CUR (zero wait). A 2-deep + B 2-deep = 56KB, 2 blocks/CU.
// ---------------------------------------------------------------------------
typedef __attribute__((address_space(1))) void gvoid;
typedef __attribute__((address_space(3))) void lvoid;
#define GLD16(g, l_) __builtin_amdgcn_global_load_lds((gvoid*)(g), (lvoid*)(l_), 16, 0, 0)
#define MF(a, b, c) __builtin_amdgcn_mfma_f32_16x16x32_bf16(a, b, c, 0, 0, 0)

#define ABUFB 16384           // 128 rows x 128B
#define BBASE 32768           // A: 2 x 16KB
#define BBUFB 12288           // 96 rows x 128B

#define STAGE_AB(T, DB) do { \
    char* da_ = Sm + (DB) * ABUFB + wid * 4096; \
    char* db_ = Sm + BBASE + (DB) * BBUFB + wid * 3072; \
    const size_t go_ = (size_t)(T) * 128; \
    GLD16(sA0 + go_, da_); \
    GLD16(sA0 + go_ + 65536, da_ + 1024); \
    GLD16(sA0 + go_ + 131072, da_ + 2048); \
    GLD16(sA0 + go_ + 196608, da_ + 3072); \
    GLD16(sB0 + go_, db_); \
    GLD16(sB0 + go_ + 65536, db_ + 1024); \
    GLD16(sB0 + go_ + 131072, db_ + 2048); \
} while (0)

#define READ_FRAGS(P, BUF) do { \
    const char* a_ = Sm + (BUF) * ABUFB + aro; \
    const char* b_ = Sm + BBASE + (BUF) * BBUFB + bro; \
    P##A0 = *(const bf16x8*)(a_); \
    P##A1 = *(const bf16x8*)(a_ + 2048); \
    P##A2 = *(const bf16x8*)(a_ + 4096); \
    P##A3 = *(const bf16x8*)(a_ + 6144); \
    P##B0 = *(const bf16x8*)(b_); \
    P##B1 = *(const bf16x8*)(b_ + 2048); \
    P##B2 = *(const bf16x8*)(b_ + 4096); \
    P##B3 = *(const bf16x8*)(b_ + 6144); \
    P##B4 = *(const bf16x8*)(b_ + 8192); \
    P##B5 = *(const bf16x8*)(b_ + 10240); \
} while (0)

#define MFMA24(P) do { \
    acc[0][0]=MF(P##A0,P##B0,acc[0][0]); acc[0][1]=MF(P##A0,P##B1,acc[0][1]); acc[0][2]=MF(P##A0,P##B2,acc[0][2]); \
    acc[0][3]=MF(P##A0,P##B3,acc[0][3]); acc[0][4]=MF(P##A0,P##B4,acc[0][4]); acc[0][5]=MF(P##A0,P##B5,acc[0][5]); \
    acc[1][0]=MF(P##A1,P##B0,acc[1][0]); acc[1][1]=MF(P##A1,P##B1,acc[1][1]); acc[1][2]=MF(P##A1,P##B2,acc[1][2]); \
    acc[1][3]=MF(P##A1,P##B3,acc[1][3]); acc[1][4]=MF(P##A1,P##B4,acc[1][4]); acc[1][5]=MF(P##A1,P##B5,acc[1][5]); \
    acc[2][0]=MF(P##A2,P##B0,acc[2][0]); acc[2][1]=MF(P##A2,P##B1,acc[2][1]); acc[2][2]=MF(P##A2,P##B2,acc[2][2]); \
    acc[2][3]=MF(P##A2,P##B3,acc[2][3]); acc[2][4]=MF(P##A2,P##B4,acc[2][4]); acc[2][5]=MF(P##A2,P##B5,acc[2][5]); \
    acc[3][0]=MF(P##A3,P##B0,acc[3][0]); acc[3][1]=MF(P##A3,P##B1,acc[3][1]); acc[3][2]=MF(P##A3,P##B2,acc[3][2]); \
    acc[3][3]=MF(P##A3,P##B3,acc[3][3]); acc[3][4]=MF(P##A3,P##B4,acc[3][4]); acc[3][5]=MF(P##A3,P##B5,acc[3][5]); \
} while (0)

// iter t: CUR = frags(t) (in regs), NXT <- frags(t+1); stage(t+2) -> buf[t&1]
#define ITER(T, CUR, NXT, DOSTAGE, DOREAD) do { \
    asm volatile("s_waitcnt vmcnt(0) lgkmcnt(0)" ::: "memory"); \
    __builtin_amdgcn_s_barrier(); \
    __builtin_amdgcn_sched_barrier(0); \
    if (DOSTAGE) STAGE_AB((T) + 2, (T) & 1); \
    if (DOREAD) READ_FRAGS(NXT, ((T) + 1) & 1); \
    __builtin_amdgcn_sched_barrier(0); \
    __builtin_amdgcn_s_setprio(1); \
    MFMA24(CUR); \
    __builtin_amdgcn_s_setprio(0); \
} while (0)

__global__ __launch_bounds__(256, 2) void gemm_fused(const u16* __restrict__ Abf,
                                                     const u16* __restrict__ Gbf,
                                                     const float* __restrict__ bt,
                                                     const float* __restrict__ bl,
                                                     const float* __restrict__ bh,
                                                     const float* __restrict__ stdv,
                                                     float* __restrict__ out) {
    __shared__ __align__(16) char Sm[57344];   // A 2x16KB | B 2x12KB
    const int tid = threadIdx.x;
    const int l = tid & 63, wid = tid >> 6;    // wid 0..3
    const int wm = wid & 1, kp = wid >> 1;

    // XCD-chunked swizzle: 512 = 8 XCDs x 64; n fastest within chunk
    const int orig = blockIdx.x;
    const int chunk = orig & 7, pos = orig >> 3;
    const int bx = pos & 7;
    const int by = (chunk << 3) + (pos >> 3);
    const int m0 = by * 128;
    const int n0 = bx * 96;

    // ---- staging: each gld16 covers 8 rows x 128B; pre-swizzled source
    //      slot = (l&7)^(l>>3)  ==>  LDS(row, s) = M(row, s ^ (row&7))
    const int sgb = (((l & 7) ^ (l >> 3)) << 4);
    const char* sA0 = (const char*)Abf + ((size_t)(m0 + wid * 32 + (l >> 3)) << 13) + sgb;
    const char* sB0 = (const char*)Gbf + ((size_t)(n0 + wid * 24 + (l >> 3)) << 13) + sgb;

    // ---- fragment read offsets (16x16x32): row base + swizzled k-slot ----
    const int slot16 = ((((kp << 2) + (l >> 4)) ^ (l & 7)) << 4);
    const int aro = (wm * 64 + (l & 15)) * 128 + slot16;   // fm adds 2048
    const int bro = (l & 15) * 128 + slot16;               // fn adds 2048

    f32x4 acc[4][6] = {};
    bf16x8 XA0, XA1, XA2, XA3, XB0, XB1, XB2, XB3, XB4, XB5;
    bf16x8 YA0, YA1, YA2, YA3, YB0, YB1, YB2, YB3, YB4, YB5;

    // ---- prologue: stage(0)->buf0 [7 ops], stage(1)->buf1 [7 ops];
    //      wait first 7; read frags(0) -> X ----
    STAGE_AB(0, 0);
    STAGE_AB(1, 1);
    asm volatile("s_waitcnt vmcnt(7)" ::: "memory");
    __builtin_amdgcn_s_barrier();
    __builtin_amdgcn_sched_barrier(0);
    READ_FRAGS(X, 0);

    for (int t = 0; t < 60; t += 2) {
        ITER(t,     X, Y, 1, 1);
        ITER(t + 1, Y, X, 1, 1);
    }
    ITER(60, X, Y, 1, 1);
    ITER(61, Y, X, 1, 1);
    ITER(62, X, Y, 0, 1);
    ITER(63, Y, X, 0, 0);

    // ---- kp-pair reduce (kp1 -> LDS, kp0 adds) + fused bias epilogue ----
    __syncthreads();
    float* red = (float*)Sm;
    const int rr = (l >> 4) << 2;
    const int cc = l & 15;
    const int rbase = wm * 6528;              // 96 cols x 68 floats
    if (kp == 1) {
        #pragma unroll
        for (int m = 0; m < 4; ++m)
            #pragma unroll
            for (int n = 0; n < 6; ++n)
                *(f32x4*)(red + rbase + (n * 16 + cc) * 68 + m * 16 + rr) = acc[m][n];
    }
    __syncthreads();
    if (kp == 0) {
        const int crow = m0 + wm * 64 + rr;
        const int ccol = n0 + cc;
        float btv[6], bsv[6];
        #pragma unroll
        for (int n = 0; n < 6; ++n) {
            const int col = ccol + n * 16;
            if (col < PCOL) { btv[n] = bt[col]; bsv[n] = bl[col] + bh[col]; }
            else            { btv[n] = 0.f; bsv[n] = 0.f; }
        }
        #pragma unroll
        for (int m = 0; m < 4; ++m) {
            const int row = crow + m * 16;
            const float4 sv = *(const float4*)(stdv + row);
            #pragma unroll
            for (int n = 0; n < 6; ++n) {
                const int col = ccol + n * 16;
                if (col < PCOL) {
                    const f32x4 pv = *(const f32x4*)(red + rbase + (n * 16 + cc) * 68 + m * 16 + rr);
                    float* orow = out + (size_t)row * PCOL + col;
                    #pragma unroll
                    for (int j = 0; j < 4; ++j) {
                        const float s = (j == 0) ? sv.x : (j == 1) ? sv.y : (j == 2) ? sv.z : sv.w;
                        orow[(size_t)j * PCOL] = acc[m][n][j] + pv[j] + btv[n] + s * bsv[n];
                    }
                }
            }
        }
    }
}

// ---------------------------------------------------------------------------
extern "C" void kernel_launch(void* const* d_in, const int* in_sizes, int n_in,
                              void* d_out, int out_size, void* d_ws, size_t ws_size,
                              hipStream_t stream) {
    (void)in_sizes; (void)n_in; (void)out_size;
    if (ws_size < WS_MIN) return;

    const float* x  = (const float*)d_in[0];
    const float* Wt = (const float*)d_in[1];
    const float* bt = (const float*)d_in[2];
    const float* Wl = (const float*)d_in[3];
    const float* bl = (const float*)d_in[4];
    const float* Wh = (const float*)d_in[5];
    const float* bh = (const float*)d_in[6];
    float* out = (float*)d_out;

    char* ws = (char*)d_ws;
    u16*   xbf = (u16*)ws;
    u16*   Gm  = (u16*)(ws + WS_XBF_BYTES);
    float* sd  = (float*)(ws + WS_XBF_BYTES + WS_G_BYTES);

    prep_rows<<<NB, 256, 0, stream>>>(x, xbf, sd);
    prep_weights<<<NPAD, 256, 0, stream>>>(Wt, Wl, Wh, Gm);
    gemm_fused<<<512, 256, 0, stream>>>(xbf, Gm, bt, bl, bh, sd, out);
}